// Round 5
// baseline (663.507 us; speedup 1.0000x reference)
//
#include <hip/hip_runtime.h>

typedef unsigned short u16;
typedef __bf16 bf16x8 __attribute__((ext_vector_type(8)));
typedef u16 u16x8 __attribute__((ext_vector_type(8)));
typedef float f32x4 __attribute__((ext_vector_type(4)));

#define S_LEN 2048
#define H_LEN 1024

__device__ __forceinline__ u16 f2b(float f) {
  unsigned u = __float_as_uint(f);
  return (u16)((u + 0x7FFFu + ((u >> 16) & 1u)) >> 16);  // RNE
}
__device__ __forceinline__ float b2f(u16 h) { return __uint_as_float(((unsigned)h) << 16); }

// C-tile chunk swizzle: spreads LDS banks for BOTH row-chunk reads and
// column reads (V-transpose). row&15 alone collapses to 2 banks on columns.
__device__ __forceinline__ int csw(int colgrp, int row) {
  return colgrp ^ (((row >> 3) + (row & 7)) & 15);
}

#define GLOAD16(gp, lp)                                   \
  __builtin_amdgcn_global_load_lds(                       \
      (__attribute__((address_space(1))) void*)(gp),      \
      (__attribute__((address_space(3))) void*)(lp), 16, 0, 0)

// ---------------- prep: casts, bias pack, relbits pack, zero d1 ---------------
__global__ __launch_bounds__(256) void prep_kernel(
    const float* __restrict__ X, const float* __restrict__ Wq,
    const float* __restrict__ Wk, const float* __restrict__ Wv,
    const float* __restrict__ bq, const float* __restrict__ bk,
    const float* __restrict__ bv, const float* __restrict__ dist,
    const int* __restrict__ rel,
    u16* __restrict__ Xbf, u16* __restrict__ Wbf, float* __restrict__ b_all,
    u16* __restrict__ de1, unsigned* __restrict__ bits, float* __restrict__ d1) {
  size_t tid = (size_t)blockIdx.x * blockDim.x + threadIdx.x;
  size_t nth = (size_t)gridDim.x * blockDim.x;
  for (size_t i = tid; i < 4194304u; i += nth) {  // X
    float4 v = ((const float4*)X)[i];
    ushort4 o; o.x = f2b(v.x); o.y = f2b(v.y); o.z = f2b(v.z); o.w = f2b(v.w);
    ((ushort4*)Xbf)[i] = o;
  }
  for (size_t i = tid; i < 786432u; i += nth) {  // Wq|Wk|Wv
    int which = (int)(i >> 18);
    size_t off = i & 262143u;
    const float4* src = (const float4*)(which == 0 ? Wq : (which == 1 ? Wk : Wv));
    float4 v = src[off];
    ushort4 o; o.x = f2b(v.x); o.y = f2b(v.y); o.z = f2b(v.z); o.w = f2b(v.w);
    ((ushort4*)Wbf)[i] = o;
  }
  // relbits: 8*2048*2048 int32 / 32 = 1048576 words, 32 elems per iter
  const int4* r4 = (const int4*)rel;
  for (size_t wi = tid; wi < 1048576u; wi += nth) {
    const int4* s = r4 + wi * 8;
    unsigned m = 0;
#pragma unroll
    for (int u = 0; u < 8; ++u) {
      int4 v = s[u];
      m |= (unsigned)(v.x == 1) << (u * 4 + 0);
      m |= (unsigned)(v.y == 1) << (u * 4 + 1);
      m |= (unsigned)(v.z == 1) << (u * 4 + 2);
      m |= (unsigned)(v.w == 1) << (u * 4 + 3);
    }
    bits[wi] = m;
  }
  for (size_t i = tid; i < 256u; i += nth) {  // dist_emb row 1
    float4 v = ((const float4*)(dist + H_LEN))[i];
    ushort4 o; o.x = f2b(v.x); o.y = f2b(v.y); o.z = f2b(v.z); o.w = f2b(v.w);
    ((ushort4*)de1)[i] = o;
  }
  for (size_t i = tid; i < 3072u; i += nth)
    b_all[i] = (i < 1024) ? bq[i] : (i < 2048 ? bk[i - 1024] : bv[i - 2048]);
  for (size_t i = tid; i < 16384u; i += nth) d1[i] = 0.f;
}

// ---------------- NT-GEMM core, BK=64, templated epilogue ---------------------
struct GArgs {
  const u16* A; const u16* B;
  long long sA, sB;
  int ldA, ldB, K, nbits;     // nbits: n-block bits for 1D XCD-swizzled grids
  u16 *Qo, *Ko, *Vt; const float* b_all; const u16* de1; float* d1;       // EPI 0
  const unsigned* relbits; const float* mask; u16* P; float* psums;       // EPI 1
  float* outp;                                                            // EPI 2
};

template <int EPI>
__global__ __launch_bounds__(256) void gemm_nt(GArgs g) {
  int bx, by, bz;
  if constexpr (EPI == 0) {   // 2D band swizzle: 8 m-blocks x 24 n-blocks
    bz = 0;
    const int lin = blockIdx.y * 24 + blockIdx.x;
    const int band = lin / (24 * 8), rem = lin % (24 * 8);
    by = band * 8 + (rem & 7);
    bx = rem >> 3;
  } else {                    // 1D grid, one batch per XCD (lin & 7), n-inner
    const int lin = blockIdx.x;
    bz = lin & 7;
    const int loc = lin >> 3;
    bx = loc & ((1 << g.nbits) - 1);
    by = loc >> g.nbits;
  }
  const u16* Abase = g.A + (size_t)bz * g.sA;
  const u16* Bbase = g.B + (size_t)bz * g.sB;
  const int m0 = by * 128, n0 = bx * 128;

  __shared__ u16 smem[16384];          // 32 KB: As|Bs during loop, C-tile after
  u16* As = smem;                      // [2 halves][128][32]
  u16* Bs = smem + 8192;

  const int tid = threadIdx.x;
  const int lane = tid & 63, w = tid >> 6;
  const int wm = w >> 1, wn = w & 1;
  const int l15 = lane & 15, quad = lane >> 4;

  f32x4 acc[4][4];
  const f32x4 zero = {0.f, 0.f, 0.f, 0.f};
#pragma unroll
  for (int a = 0; a < 4; ++a)
#pragma unroll
    for (int b = 0; b < 4; ++b) acc[a][b] = zero;

  const int c0 = tid, c1 = tid + 256;
  const u16* ga0 = Abase + (size_t)(m0 + (c0 >> 2)) * g.ldA + (c0 & 3) * 8;
  const u16* ga1 = Abase + (size_t)(m0 + (c1 >> 2)) * g.ldA + (c1 & 3) * 8;
  const u16* gb0 = Bbase + (size_t)(n0 + (c0 >> 2)) * g.ldB + (c0 & 3) * 8;
  const u16* gb1 = Bbase + (size_t)(n0 + (c1 >> 2)) * g.ldB + (c1 & 3) * 8;
  u16* la0 = As + c0 * 8; u16* la1 = As + c1 * 8;
  u16* lb0 = Bs + c0 * 8; u16* lb1 = Bs + c1 * 8;

  for (int kt = 0; kt < g.K; kt += 64) {
    __syncthreads();
    GLOAD16(ga0 + kt, la0);      GLOAD16(ga0 + kt + 32, la0 + 4096);
    GLOAD16(ga1 + kt, la1);      GLOAD16(ga1 + kt + 32, la1 + 4096);
    GLOAD16(gb0 + kt, lb0);      GLOAD16(gb0 + kt + 32, lb0 + 4096);
    GLOAD16(gb1 + kt, lb1);      GLOAD16(gb1 + kt + 32, lb1 + 4096);
    __syncthreads();
#pragma unroll
    for (int s = 0; s < 2; ++s) {
      bf16x8 af[4], bfb[4];
#pragma unroll
      for (int t = 0; t < 4; ++t) {
        af[t]  = *(const bf16x8*)&As[s * 4096 + (wm * 64 + t * 16 + l15) * 32 + quad * 8];
        bfb[t] = *(const bf16x8*)&Bs[s * 4096 + (wn * 64 + t * 16 + l15) * 32 + quad * 8];
      }
#pragma unroll
      for (int mt = 0; mt < 4; ++mt)
#pragma unroll
        for (int nt = 0; nt < 4; ++nt)
          acc[mt][nt] = __builtin_amdgcn_mfma_f32_16x16x32_bf16(af[mt], bfb[nt], acc[mt][nt], 0, 0, 0);
    }
  }
  __syncthreads();  // smem becomes the C staging tile

  const int nbase = n0 + wn * 64;
  // C/D layout: col = lane&15, row = quad*4 + reg

  if constexpr (EPI == 0) {  // QKV: +bias, d1 partial, coalesced store (Q/K) or V^T
    const int which = n0 >> 10;             // uniform per block
    float bv4[4], dw[4];
#pragma unroll
    for (int nt = 0; nt < 4; ++nt) {
      bv4[nt] = g.b_all[nbase + nt * 16 + l15];
      dw[nt] = (which == 0) ? b2f(g.de1[nbase + nt * 16 + l15]) : 0.f;
    }
#pragma unroll
    for (int mt = 0; mt < 4; ++mt)
#pragma unroll
      for (int r = 0; r < 4; ++r) {
        const int row = wm * 64 + mt * 16 + quad * 4 + r;
        float part = 0.f;
#pragma unroll
        for (int nt = 0; nt < 4; ++nt) {
          const float v = acc[mt][nt][r] + bv4[nt];
          part += v * dw[nt];
          const int col = wn * 64 + nt * 16 + l15;
          smem[row * 128 + csw(col >> 3, row) * 8 + (col & 7)] = f2b(v);
        }
        if (which == 0) {
          part += __shfl_xor(part, 1);
          part += __shfl_xor(part, 2);
          part += __shfl_xor(part, 4);
          part += __shfl_xor(part, 8);
          if (l15 == 0) atomicAdd(&g.d1[m0 + row], part);
        }
      }
    __syncthreads();
    if (which < 2) {  // Q/K: row-major coalesced 16B stores
      u16* dstbuf = which == 0 ? g.Qo : g.Ko;
      const int nl0 = n0 & 1023;
#pragma unroll
      for (int p = 0; p < 8; ++p) {
        const int flat = p * 256 + tid;
        const int row = flat >> 4, chunk = flat & 15;
        u16x8 v = *(const u16x8*)&smem[row * 128 + csw(chunk, row) * 8];
        *(u16x8*)(dstbuf + (size_t)(m0 + row) * H_LEN + nl0 + chunk * 8) = v;
      }
    } else {          // V: transposed store -> Vt[b][d][j], coalesced 16B in j
      const int b = m0 >> 11, j0 = m0 & 2047, dg0 = n0 - 2048;
#pragma unroll
      for (int p = 0; p < 8; ++p) {
        const int flat = p * 256 + tid;
        const int dcol = flat >> 4, ich = flat & 15;
        u16x8 v;
#pragma unroll
        for (int s = 0; s < 8; ++s) {
          const int row = ich * 8 + s;
          v[s] = smem[row * 128 + csw(dcol >> 3, row) * 8 + (dcol & 7)];
        }
        *(u16x8*)(g.Vt + ((size_t)b * H_LEN + dg0 + dcol) * S_LEN + j0 + ich * 8) = v;
      }
    }
  }

  if constexpr (EPI == 1) {  // scores: bitmask bias + exp, P store, psums partials
    float mk[4];
#pragma unroll
    for (int nt = 0; nt < 4; ++nt) mk[nt] = g.mask[bz * S_LEN + nbase + nt * 16 + l15];
    const size_t bSS = (size_t)bz * S_LEN * S_LEN;
#pragma unroll
    for (int mt = 0; mt < 4; ++mt)
#pragma unroll
      for (int r = 0; r < 4; ++r) {
        const int row = wm * 64 + mt * 16 + quad * 4 + r;
        const int gi = bz * S_LEN + m0 + row;
        const float d1v = g.d1[gi] * 0.03125f;
        const unsigned w0 = g.relbits[(size_t)gi * 64 + (nbase >> 5)];
        const unsigned w1 = g.relbits[(size_t)gi * 64 + (nbase >> 5) + 1];
        float psum = 0.f;
#pragma unroll
        for (int nt = 0; nt < 4; ++nt) {
          const unsigned word = (nt & 2) ? w1 : w0;
          const int pos = (nt * 16 + l15) & 31;
          const float bias = ((word >> pos) & 1) ? d1v : 0.f;
          const float logit = acc[mt][nt][r] * 0.03125f + bias + mk[nt];
          const float pv = __expf(logit);  // logits bounded, no max-shift
          psum += pv;
          const int col = wn * 64 + nt * 16 + l15;
          smem[row * 128 + csw(col >> 3, row) * 8 + (col & 7)] = f2b(pv);
        }
        psum += __shfl_xor(psum, 1);
        psum += __shfl_xor(psum, 2);
        psum += __shfl_xor(psum, 4);
        psum += __shfl_xor(psum, 8);
        if (l15 == 0) g.psums[(size_t)gi * 32 + bx * 2 + wn] = psum;  // no atomic
      }
    __syncthreads();
#pragma unroll
    for (int p = 0; p < 8; ++p) {
      const int flat = p * 256 + tid;
      const int row = flat >> 4, chunk = flat & 15;
      u16x8 v = *(const u16x8*)&smem[row * 128 + csw(chunk, row) * 8];
      *(u16x8*)(g.P + bSS + (size_t)(m0 + row) * S_LEN + n0 + chunk * 8) = v;
    }
  }

  if constexpr (EPI == 2) {  // ctx: normalize by psums total, fp32 store
    const size_t ob = (size_t)bz * S_LEN * H_LEN;
#pragma unroll
    for (int mt = 0; mt < 4; ++mt)
#pragma unroll
      for (int r = 0; r < 4; ++r) {
        const int i = m0 + wm * 64 + mt * 16 + quad * 4 + r;
        const size_t gi = (size_t)bz * S_LEN + i;
        float part = g.psums[gi * 32 + l15] + g.psums[gi * 32 + 16 + l15];
        part += __shfl_xor(part, 1);
        part += __shfl_xor(part, 2);
        part += __shfl_xor(part, 4);
        part += __shfl_xor(part, 8);
        const float inv = 1.0f / part;
        const size_t rowo = ob + (size_t)i * H_LEN;
#pragma unroll
        for (int nt = 0; nt < 4; ++nt) {
          const int d = n0 + wn * 64 + nt * 16 + l15;
          g.outp[rowo + d] = acc[mt][nt][r] * inv;
        }
      }
  }
}

extern "C" void kernel_launch(void* const* d_in, const int* in_sizes, int n_in,
                              void* d_out, int out_size, void* d_ws, size_t ws_size,
                              hipStream_t stream) {
  (void)in_sizes; (void)n_in; (void)out_size; (void)ws_size;
  const float* X    = (const float*)d_in[0];
  const float* mask = (const float*)d_in[1];
  const int*   rel  = (const int*)d_in[2];
  const float* Wq   = (const float*)d_in[3];
  const float* bq   = (const float*)d_in[4];
  const float* Wk   = (const float*)d_in[5];
  const float* bk   = (const float*)d_in[6];
  const float* Wv   = (const float*)d_in[7];
  const float* bv   = (const float*)d_in[8];
  const float* dist = (const float*)d_in[9];
  float* out = (float*)d_out;

  char* p = (char*)d_ws;
  u16* Xbf = (u16*)p;      p += (size_t)16384 * 1024 * 2;
  u16* Wbf = (u16*)p;      p += (size_t)3072 * 1024 * 2;
  float* b_all = (float*)p; p += 3072 * 4;
  u16* de1 = (u16*)p;      p += 4096;
  u16* Qb = (u16*)p;       p += (size_t)16384 * 1024 * 2;
  u16* Kb = (u16*)p;       p += (size_t)16384 * 1024 * 2;
  u16* Vt = (u16*)p;       p += (size_t)16384 * 1024 * 2;
  float* d1 = (float*)p;   p += 16384 * 4;
  float* psums = (float*)p; p += (size_t)16384 * 32 * 4;
  unsigned* relbits = (unsigned*)p; p += (size_t)1048576 * 4;
  u16* P = (u16*)p;        p += (size_t)8 * 2048 * 2048 * 2;

  prep_kernel<<<1024, 256, 0, stream>>>(X, Wq, Wk, Wv, bq, bk, bv, dist, rel,
                                        Xbf, Wbf, b_all, de1, relbits, d1);

  // QKV: [16384x1024] @ [3072x1024]^T ; V written transposed
  GArgs g0 = {};
  g0.A = Xbf; g0.B = Wbf; g0.sA = 0; g0.sB = 0;
  g0.ldA = 1024; g0.ldB = 1024; g0.K = 1024;
  g0.Qo = Qb; g0.Ko = Kb; g0.Vt = Vt; g0.b_all = b_all; g0.de1 = de1; g0.d1 = d1;
  gemm_nt<0><<<dim3(24, 128, 1), dim3(256, 1, 1), 0, stream>>>(g0);

  // scores+exp: per batch [2048x1024] @ [2048x1024]^T ; 1 batch per XCD
  GArgs g1 = {};
  g1.A = Qb; g1.B = Kb; g1.sA = 2048LL * 1024; g1.sB = 2048LL * 1024;
  g1.ldA = 1024; g1.ldB = 1024; g1.K = 1024; g1.nbits = 4;
  g1.relbits = relbits; g1.d1 = d1; g1.mask = mask; g1.P = P; g1.psums = psums;
  gemm_nt<1><<<dim3(2048, 1, 1), dim3(256, 1, 1), 0, stream>>>(g1);

  // ctx: per batch [2048x2048] @ [1024x2048]^T (Vt) ; 1 batch per XCD
  GArgs g2 = {};
  g2.A = P; g2.B = Vt; g2.sA = 2048LL * 2048; g2.sB = 1024LL * 2048;
  g2.ldA = 2048; g2.ldB = 2048; g2.K = 2048; g2.nbits = 3;
  g2.psums = psums; g2.outp = out;
  gemm_nt<2><<<dim3(1024, 1, 1), dim3(256, 1, 1), 0, stream>>>(g2);
}